// Round 5
// baseline (641.318 us; speedup 1.0000x reference)
//
#include <hip/hip_runtime.h>
#include <hip/hip_bf16.h>
#include <math.h>

#define NN 20000
#define NE 320000
#define NG 128

using bf16x8 = __attribute__((ext_vector_type(8))) short;
using f32x4  = __attribute__((ext_vector_type(4))) float;

static __device__ __forceinline__ float lrelu(float v){ return v > 0.f ? v : 0.2f*v; }
static __device__ __forceinline__ float b2f(unsigned short u){ unsigned int v = ((unsigned int)u) << 16; return __uint_as_float(v); }
static __device__ __forceinline__ unsigned short f2b(float f){
  unsigned int x = __float_as_uint(f);
  unsigned int r = x + 0x7fffu + ((x >> 16) & 1u);
  return (unsigned short)(r >> 16);
}
static __device__ __forceinline__ void gl16(const unsigned short* g, unsigned short* l){
  __builtin_amdgcn_global_load_lds((const __attribute__((address_space(1))) void*)g,
                                   (__attribute__((address_space(3))) void*)l, 16, 0, 0);
}

// ---------------- CSR build ----------------
__global__ void k_hist2(const int* __restrict__ dst, const int* __restrict__ batch,
                        int* __restrict__ deg, int* __restrict__ gdeg){
  int i = blockIdx.x*blockDim.x + threadIdx.x;
  if (i < NE) atomicAdd(&deg[dst[i]], 1);
  else if (i < NE + NN) atomicAdd(&gdeg[batch[i - NE]], 1);
}

static __device__ void scan_seq(const int* __restrict__ deg, int* __restrict__ ptr, int n){
  __shared__ int tmp[1024];
  __shared__ int carry;
  int t = threadIdx.x;
  if (t == 0){ carry = 0; ptr[0] = 0; }
  __syncthreads();
  for (int c0 = 0; c0 < n; c0 += 1024){
    int v = (c0 + t < n) ? deg[c0 + t] : 0;
    tmp[t] = v; __syncthreads();
    for (int off = 1; off < 1024; off <<= 1){
      int u = (t >= off) ? tmp[t - off] : 0;
      __syncthreads();
      tmp[t] += u;
      __syncthreads();
    }
    if (c0 + t < n) ptr[c0 + t + 1] = carry + tmp[t];
    __syncthreads();
    if (t == 0) carry += tmp[1023];
    __syncthreads();
  }
}

__global__ void k_scan2(const int* __restrict__ deg, int* __restrict__ rowptr,
                        const int* __restrict__ gdeg, int* __restrict__ gptr){
  if (blockIdx.x == 0) scan_seq(deg, rowptr, NN);
  else                 scan_seq(gdeg, gptr, NG);
}

__global__ void k_fill(const int* __restrict__ src, const int* __restrict__ dst,
                       const int* __restrict__ ptr, int* __restrict__ cnt,
                       int* __restrict__ csrc){
  int e = blockIdx.x*blockDim.x + threadIdx.x;
  if (e < NE){
    int d = dst[e];
    int p = atomicAdd(&cnt[d], 1);
    csrc[ptr[d] + p] = src[e];
  }
}

// ---------------- weight prep: coalesced 64x64 tile transpose + x cast ----------------
struct WPrep {
  const float* W[9];
  unsigned short* Wt[9];
  int K[9];
  int Nn[9];
  int tileStart[10];
  const float* x;
  unsigned int* xb;
};

__global__ __launch_bounds__(256)
void k_prep2(WPrep P){
  __shared__ float tile[64][65];
  int b = blockIdx.x;
  if (b < P.tileStart[9]){
    int i = 0;
    while (i < 8 && b >= P.tileStart[i+1]) i++;
    int ti = b - P.tileStart[i];
    int K = P.K[i], Nn = P.Nn[i];
    int ntc = Nn >> 6;
    int k0 = (ti / ntc) << 6, n0 = (ti % ntc) << 6;
    int c = threadIdx.x & 63, ro = threadIdx.x >> 6;
    const float* W = P.W[i];
    #pragma unroll
    for (int rr = 0; rr < 16; rr++){
      int r = rr*4 + ro;
      tile[c][r] = W[(size_t)(k0 + r)*Nn + n0 + c];
    }
    __syncthreads();
    unsigned short* Wt = P.Wt[i];
    #pragma unroll
    for (int cc = 0; cc < 16; cc++){
      int cidx = cc*4 + ro;
      Wt[(size_t)(n0 + cidx)*K + k0 + c] = f2b(tile[cidx][c]);
    }
  } else {
    int idx = (b - P.tileStart[9])*256 + threadIdx.x;
    if (idx < NN*64){
      unsigned int lo = f2b(P.x[2*idx]);
      unsigned int hi = f2b(P.x[2*idx + 1]);
      P.xb[idx] = lo | (hi << 16);
    }
  }
}

// ---------------- unified GIN aggregation ----------------
// MODE 0: z = self + sum(neighbors)                     (plain bf16 gather)
// MODE 1: z = bnrelu(self) + sum bnrelu(neighbors)      (BN fused into gather; stats in double)
// MODE 2: z = relu(self + sum(neighbors) + bias)        (post-w1 agg for gin4)
// DU = d/2 uint lanes per node; 256/DU nodes per block; no barriers in edge loop.
template<int MODE, int DU>
__global__ __launch_bounds__(256)
void k_agg(const unsigned int* __restrict__ hU, const int* __restrict__ ptr,
           const int* __restrict__ csrc, unsigned int* __restrict__ z,
           const double* __restrict__ stats, const float* __restrict__ g,
           const float* __restrict__ bb, const float* __restrict__ bias){
  const int d = DU*2;
  __shared__ float scs[MODE == 1 ? 512 : 1];
  __shared__ float shs[MODE == 1 ? 512 : 1];
  int t = threadIdx.x;
  if (MODE == 1){
    for (int f = t; f < d; f += 256){
      double inv = 1.0 / (double)NN;
      double mu  = stats[f]*inv;
      double var = stats[d + f]*inv - mu*mu;
      if (var < 0.0) var = 0.0;
      float sc = g[f] * rsqrtf((float)var + 1e-5f);
      scs[f] = sc;
      shs[f] = bb[f] - (float)mu*sc;
    }
    __syncthreads();
  }
  const int npb = 256/DU;
  int n  = blockIdx.x*npb + t/DU;
  int tl = t & (DU - 1);
  int f0 = 2*tl, f1 = f0 + 1;
  float sc0 = 0.f, sh0 = 0.f, sc1 = 0.f, sh1 = 0.f;
  if (MODE == 1){ sc0 = scs[f0]; sh0 = shs[f0]; sc1 = scs[f1]; sh1 = shs[f1]; }
  int beg = ptr[n], deg = ptr[n+1] - beg;
  unsigned int self = hU[(size_t)n*DU + tl];
  float a0, a1;
  if (MODE == 1){
    a0 = fmaxf(b2f(self & 0xffff)*sc0 + sh0, 0.f);
    a1 = fmaxf(b2f(self >> 16)   *sc1 + sh1, 0.f);
  } else {
    a0 = b2f(self & 0xffff);
    a1 = b2f(self >> 16);
  }
  int i = 0;
  for (; i + 4 <= deg; i += 4){
    int s0 = csrc[beg + i], s1 = csrc[beg + i + 1], s2 = csrc[beg + i + 2], s3 = csrc[beg + i + 3];
    unsigned int v0 = hU[(size_t)s0*DU + tl];
    unsigned int v1 = hU[(size_t)s1*DU + tl];
    unsigned int v2 = hU[(size_t)s2*DU + tl];
    unsigned int v3 = hU[(size_t)s3*DU + tl];
    if (MODE == 1){
      a0 += fmaxf(b2f(v0 & 0xffff)*sc0 + sh0, 0.f) + fmaxf(b2f(v1 & 0xffff)*sc0 + sh0, 0.f)
          + fmaxf(b2f(v2 & 0xffff)*sc0 + sh0, 0.f) + fmaxf(b2f(v3 & 0xffff)*sc0 + sh0, 0.f);
      a1 += fmaxf(b2f(v0 >> 16)*sc1 + sh1, 0.f) + fmaxf(b2f(v1 >> 16)*sc1 + sh1, 0.f)
          + fmaxf(b2f(v2 >> 16)*sc1 + sh1, 0.f) + fmaxf(b2f(v3 >> 16)*sc1 + sh1, 0.f);
    } else {
      a0 += b2f(v0 & 0xffff) + b2f(v1 & 0xffff) + b2f(v2 & 0xffff) + b2f(v3 & 0xffff);
      a1 += b2f(v0 >> 16)    + b2f(v1 >> 16)    + b2f(v2 >> 16)    + b2f(v3 >> 16);
    }
  }
  for (; i < deg; i++){
    int s = csrc[beg + i];
    unsigned int v = hU[(size_t)s*DU + tl];
    if (MODE == 1){
      a0 += fmaxf(b2f(v & 0xffff)*sc0 + sh0, 0.f);
      a1 += fmaxf(b2f(v >> 16)   *sc1 + sh1, 0.f);
    } else {
      a0 += b2f(v & 0xffff);
      a1 += b2f(v >> 16);
    }
  }
  if (MODE == 2){
    a0 = fmaxf(a0 + bias[f0], 0.f);
    a1 = fmaxf(a1 + bias[f1], 0.f);
  }
  z[(size_t)n*DU + tl] = (unsigned int)f2b(a0) | ((unsigned int)f2b(a1) << 16);
}

// ---------------- bf16 MFMA GEMM (2-phase double-buffered global_load_lds) ----------------
template<int ACT, int OBF, int STATS, int SCORES>
__global__ __launch_bounds__(256)
void k_gemm_mfma(const unsigned short* __restrict__ A, const unsigned short* __restrict__ Bt,
                 const float* __restrict__ bias, float* __restrict__ C,
                 unsigned short* __restrict__ Cb, double* __restrict__ stats,
                 const float* __restrict__ asrc, const float* __restrict__ adst,
                 float* __restrict__ a_s, float* __restrict__ a_d,
                 int M, int Nn, int K){
  __shared__ unsigned short As[2][128*32];
  __shared__ unsigned short Bs[2][128*32];
  __shared__ float sS[SCORES ? 128 : 1];
  __shared__ float sD[SCORES ? 128 : 1];
  const int bm = blockIdx.y*128, bn = blockIdx.x*128;
  const int tid = threadIdx.x;
  const int lane = tid & 63;
  const int wave = tid >> 6;
  const int wm = (wave >> 1)*64, wn = (wave & 1)*64;
  const int lr = lane & 15, lq = lane >> 4;

  f32x4 acc[4][4];
  #pragma unroll
  for (int i = 0; i < 4; i++)
    #pragma unroll
    for (int j = 0; j < 4; j++) acc[i][j] = (f32x4){0.f,0.f,0.f,0.f};

  const int rowA = tid >> 2, q = tid & 3;
  const int ldsOff = wave*16*32;
  const int gmA0 = min(bm + rowA,      M-1);
  const int gmA1 = min(bm + rowA + 64, M-1);
  const unsigned short* pA0 = &A[(size_t)gmA0*K + q*8];
  const unsigned short* pA1 = &A[(size_t)gmA1*K + q*8];
  const unsigned short* pB0 = &Bt[(size_t)(bn + rowA)*K + q*8];
  const unsigned short* pB1 = &Bt[(size_t)(bn + rowA + 64)*K + q*8];

  // prologue stage
  gl16(pA0, &As[0][ldsOff]);
  gl16(pA1, &As[0][ldsOff] + 64*32);
  gl16(pB0, &Bs[0][ldsOff]);
  gl16(pB1, &Bs[0][ldsOff] + 64*32);
  __syncthreads();

  int cur = 0;
  for (int k0 = 0; k0 < K; k0 += 32){
    if (k0 + 32 < K){
      int kn = k0 + 32;
      gl16(pA0 + kn, &As[cur^1][ldsOff]);
      gl16(pA1 + kn, &As[cur^1][ldsOff] + 64*32);
      gl16(pB0 + kn, &Bs[cur^1][ldsOff]);
      gl16(pB1 + kn, &Bs[cur^1][ldsOff] + 64*32);
    }
    bf16x8 af[4], bf[4];
    #pragma unroll
    for (int mi = 0; mi < 4; mi++)
      af[mi] = *(const bf16x8*)&As[cur][(wm + mi*16 + lr)*32 + lq*8];
    #pragma unroll
    for (int ni = 0; ni < 4; ni++)
      bf[ni] = *(const bf16x8*)&Bs[cur][(wn + ni*16 + lr)*32 + lq*8];
    #pragma unroll
    for (int mi = 0; mi < 4; mi++)
      #pragma unroll
      for (int ni = 0; ni < 4; ni++)
        acc[mi][ni] = __builtin_amdgcn_mfma_f32_16x16x32_bf16(af[mi], bf[ni], acc[mi][ni], 0, 0, 0);
    __syncthreads();          // compiler drains vmcnt before barrier -> next buffer ready
    cur ^= 1;
  }

  float cs[4] = {0.f,0.f,0.f,0.f}, cq[4] = {0.f,0.f,0.f,0.f};
  #pragma unroll
  for (int mi = 0; mi < 4; mi++){
    #pragma unroll
    for (int j = 0; j < 4; j++){
      int gm = bm + wm + mi*16 + lq*4 + j;
      if (gm < M){
        #pragma unroll
        for (int ni = 0; ni < 4; ni++){
          int gn = bn + wn + ni*16 + lr;
          float v = acc[mi][ni][j] + (bias ? bias[gn] : 0.f);
          if (ACT) v = fmaxf(v, 0.f);
          if (OBF) Cb[(size_t)gm*Nn + gn] = f2b(v);
          else     C [(size_t)gm*Nn + gn] = v;
          if (STATS){ cs[ni] += v; cq[ni] += v*v; }
        }
      }
    }
  }
  if (STATS){
    #pragma unroll
    for (int ni = 0; ni < 4; ni++){
      float s = cs[ni], qq = cq[ni];
      s += __shfl_xor(s, 16); s += __shfl_xor(s, 32);
      qq += __shfl_xor(qq, 16); qq += __shfl_xor(qq, 32);
      if (lane < 16){
        int gn = bn + wn + ni*16 + lr;
        atomicAdd(&stats[gn],      (double)s);
        atomicAdd(&stats[Nn + gn], (double)qq);
      }
    }
  }
  if (SCORES){
    const int hd = bn >> 7;
    float av[4], dv[4];
    #pragma unroll
    for (int ni = 0; ni < 4; ni++){
      int c = wn + ni*16 + lr;
      av[ni] = asrc[hd*128 + c];
      dv[ni] = adst[hd*128 + c];
    }
    float psS[4][4], psD[4][4];
    #pragma unroll
    for (int mi = 0; mi < 4; mi++)
      #pragma unroll
      for (int j = 0; j < 4; j++){
        float s = 0.f, d2 = 0.f;
        #pragma unroll
        for (int ni = 0; ni < 4; ni++){
          float v = acc[mi][ni][j];
          s  += v*av[ni];
          d2 += v*dv[ni];
        }
        #pragma unroll
        for (int o = 1; o < 16; o <<= 1){ s += __shfl_xor(s, o); d2 += __shfl_xor(d2, o); }
        psS[mi][j] = s; psD[mi][j] = d2;
      }
    if (wn == 0 && lr == 0){
      #pragma unroll
      for (int mi = 0; mi < 4; mi++)
        #pragma unroll
        for (int j = 0; j < 4; j++){
          int r = wm + mi*16 + lq*4 + j;
          sS[r] = psS[mi][j]; sD[r] = psD[mi][j];
        }
    }
    __syncthreads();
    if (wn != 0 && lr == 0){
      #pragma unroll
      for (int mi = 0; mi < 4; mi++)
        #pragma unroll
        for (int j = 0; j < 4; j++){
          int r = wm + mi*16 + lq*4 + j;
          sS[r] += psS[mi][j]; sD[r] += psD[mi][j];
        }
    }
    __syncthreads();
    if (tid < 128){
      int gm = bm + tid;
      if (gm < M){ a_s[gm*8 + hd] = sS[tid]; a_d[gm*8 + hd] = sD[tid]; }
    }
  }
}

// ---------------- BatchNorm ----------------
__global__ void k_bn_stats16(const unsigned short* __restrict__ h, int d, double* __restrict__ stats){
  int r0 = blockIdx.x*64;
  int rend = min(NN, r0 + 64);
  for (int f = threadIdx.x; f < d; f += blockDim.x){
    float s = 0.f, q = 0.f;
    for (int r = r0; r < rend; r++){ float v = b2f(h[(size_t)r*d + f]); s += v; q += v*v; }
    atomicAdd(&stats[f], (double)s);
    atomicAdd(&stats[d + f], (double)q);
  }
}

template<int GATE>
__global__ __launch_bounds__(256)
void k_bn_relu16(const unsigned short* __restrict__ hpre, unsigned short* __restrict__ hb,
                 int total8, int dmask, int d, const double* __restrict__ stats,
                 const float* __restrict__ g, const float* __restrict__ b,
                 const float* __restrict__ gatew, const float* __restrict__ gateb,
                 float* __restrict__ logit){
  __shared__ float scs[512], shs[512];
  for (int f = threadIdx.x; f < d; f += blockDim.x){
    double inv = 1.0 / (double)NN;
    double mu  = stats[f]*inv;
    double var = stats[d + f]*inv - mu*mu;
    if (var < 0.0) var = 0.0;
    float sc = g[f] * rsqrtf((float)var + 1e-5f);
    scs[f] = sc;
    shs[f] = b[f] - (float)mu*sc;
  }
  __syncthreads();
  int i = blockIdx.x*blockDim.x + threadIdx.x;
  if (i >= total8) return;
  int i8 = i*8;
  uint4 u = *(const uint4*)&hpre[i8];
  float v[8] = { b2f(u.x & 0xffff), b2f(u.x >> 16), b2f(u.y & 0xffff), b2f(u.y >> 16),
                 b2f(u.z & 0xffff), b2f(u.z >> 16), b2f(u.w & 0xffff), b2f(u.w >> 16) };
  int f0 = i8 & dmask;
  float gp = 0.f;
  #pragma unroll
  for (int j = 0; j < 8; j++){
    float y = fmaxf(v[j]*scs[f0 + j] + shs[f0 + j], 0.f);
    v[j] = y;
    if (GATE) gp += y*gatew[f0 + j];
  }
  uint4 p;
  p.x = (unsigned int)f2b(v[0]) | ((unsigned int)f2b(v[1]) << 16);
  p.y = (unsigned int)f2b(v[2]) | ((unsigned int)f2b(v[3]) << 16);
  p.z = (unsigned int)f2b(v[4]) | ((unsigned int)f2b(v[5]) << 16);
  p.w = (unsigned int)f2b(v[6]) | ((unsigned int)f2b(v[7]) << 16);
  *(uint4*)&hb[i8] = p;
  if (GATE){
    #pragma unroll
    for (int o = 1; o < 16; o <<= 1) gp += __shfl_xor(gp, o);
    if ((threadIdx.x & 15) == 0) logit[i >> 4] = gp + gateb[0];
  }
}

// ---------------- GAT node aggregate (writes bf16) ----------------
__global__ __launch_bounds__(256)
void k_gat_node256(const unsigned short* __restrict__ xh, const float* __restrict__ a_s,
                   const float* __restrict__ a_d, const int* __restrict__ ptr,
                   const int* __restrict__ csrc, const float* __restrict__ bias,
                   unsigned short* __restrict__ hout){
  int n = blockIdx.x, t = threadIdx.x;
  int beg = ptr[n], deg = ptr[n+1] - beg;
  int tot = deg + 1;
  __shared__ float elv[256][9];
  __shared__ int esrc[256];
  __shared__ float red[256];
  __shared__ float ms[8], ssinv[8], adn[8];
  __shared__ float partial[16][132];
  if (t < 8) adn[t] = a_d[n*8 + t];
  __syncthreads();
  int head = t >> 5, slot = t & 31;
  int sub = t >> 7, tt = t & 127;
  int h16 = tt >> 4;
  float acc[8] = {0.f,0.f,0.f,0.f,0.f,0.f,0.f,0.f};

  if (tot <= 256){
    for (int i = t; i < tot; i += 256) esrc[i] = (i < deg) ? csrc[beg + i] : n;
    __syncthreads();
    for (int i = t; i < tot*8; i += 256){
      int le = i >> 3, hh = i & 7;
      elv[le][hh] = lrelu(a_s[esrc[le]*8 + hh] + adn[hh]);
    }
    __syncthreads();
    float mx = -1e30f;
    for (int e = slot; e < tot; e += 32) mx = fmaxf(mx, elv[e][head]);
    red[t] = mx; __syncthreads();
    #pragma unroll
    for (int off = 16; off >= 1; off >>= 1){
      if (slot < off) red[t] = fmaxf(red[t], red[t + off]);
      __syncthreads();
    }
    if (slot == 0) ms[head] = red[t];
    __syncthreads();
    float sm = 0.f;
    for (int e = slot; e < tot; e += 32){
      float ex = __expf(elv[e][head] - ms[head]);
      elv[e][head] = ex;
      sm += ex;
    }
    red[t] = sm; __syncthreads();
    #pragma unroll
    for (int off = 16; off >= 1; off >>= 1){
      if (slot < off) red[t] += red[t + off];
      __syncthreads();
    }
    if (slot == 0) ssinv[head] = 1.f / (red[t] + 1e-16f);
    __syncthreads();
    int lo = sub*128, hi = min(tot, lo + 128);
    float si = ssinv[h16];
    int i = lo;
    for (; i + 2 <= hi; i += 2){
      const uint4* r0 = (const uint4*)(xh + (size_t)esrc[i]*1024);
      const uint4* r1 = (const uint4*)(xh + (size_t)esrc[i+1]*1024);
      uint4 v0 = r0[tt], v1 = r1[tt];
      float a0 = elv[i][h16]*si, a1 = elv[i+1][h16]*si;
      acc[0] += a0*b2f(v0.x & 0xffff) + a1*b2f(v1.x & 0xffff);
      acc[1] += a0*b2f(v0.x >> 16)    + a1*b2f(v1.x >> 16);
      acc[2] += a0*b2f(v0.y & 0xffff) + a1*b2f(v1.y & 0xffff);
      acc[3] += a0*b2f(v0.y >> 16)    + a1*b2f(v1.y >> 16);
      acc[4] += a0*b2f(v0.z & 0xffff) + a1*b2f(v1.z & 0xffff);
      acc[5] += a0*b2f(v0.z >> 16)    + a1*b2f(v1.z >> 16);
      acc[6] += a0*b2f(v0.w & 0xffff) + a1*b2f(v1.w & 0xffff);
      acc[7] += a0*b2f(v0.w >> 16)    + a1*b2f(v1.w >> 16);
    }
    for (; i < hi; i++){
      const uint4* r0 = (const uint4*)(xh + (size_t)esrc[i]*1024);
      uint4 v0 = r0[tt];
      float a0 = elv[i][h16]*si;
      acc[0] += a0*b2f(v0.x & 0xffff); acc[1] += a0*b2f(v0.x >> 16);
      acc[2] += a0*b2f(v0.y & 0xffff); acc[3] += a0*b2f(v0.y >> 16);
      acc[4] += a0*b2f(v0.z & 0xffff); acc[5] += a0*b2f(v0.z >> 16);
      acc[6] += a0*b2f(v0.w & 0xffff); acc[7] += a0*b2f(v0.w >> 16);
    }
    __syncthreads();
  } else {
    float mx = -1e30f;
    for (int e = slot; e < tot; e += 32){
      int s = (e < deg) ? csrc[beg + e] : n;
      mx = fmaxf(mx, lrelu(a_s[s*8 + head] + adn[head]));
    }
    red[t] = mx; __syncthreads();
    #pragma unroll
    for (int off = 16; off >= 1; off >>= 1){
      if (slot < off) red[t] = fmaxf(red[t], red[t + off]);
      __syncthreads();
    }
    if (slot == 0) ms[head] = red[t];
    __syncthreads();
    float sm = 0.f;
    for (int e = slot; e < tot; e += 32){
      int s = (e < deg) ? csrc[beg + e] : n;
      sm += __expf(lrelu(a_s[s*8 + head] + adn[head]) - ms[head]);
    }
    red[t] = sm; __syncthreads();
    #pragma unroll
    for (int off = 16; off >= 1; off >>= 1){
      if (slot < off) red[t] += red[t + off];
      __syncthreads();
    }
    if (slot == 0) ssinv[head] = 1.f / (red[t] + 1e-16f);
    __syncthreads();
    float si = ssinv[h16];
    for (int ch = 0; ch < tot; ch += 256){
      int ce = min(256, tot - ch);
      for (int i = t; i < ce*8; i += 256){
        int le = i >> 3, hh = i & 7;
        int s = (ch + le < deg) ? csrc[beg + ch + le] : n;
        if (hh == 0) esrc[le] = s;
        elv[le][hh] = __expf(lrelu(a_s[s*8 + hh] + adn[hh]) - ms[hh]);
      }
      __syncthreads();
      int lo = sub*128, hi = min(ce, lo + 128);
      for (int i = lo; i < hi; i++){
        const uint4* r0 = (const uint4*)(xh + (size_t)esrc[i]*1024);
        uint4 v0 = r0[tt];
        float a0 = elv[i][h16]*si;
        acc[0] += a0*b2f(v0.x & 0xffff); acc[1] += a0*b2f(v0.x >> 16);
        acc[2] += a0*b2f(v0.y & 0xffff); acc[3] += a0*b2f(v0.y >> 16);
        acc[4] += a0*b2f(v0.z & 0xffff); acc[5] += a0*b2f(v0.z >> 16);
        acc[6] += a0*b2f(v0.w & 0xffff); acc[7] += a0*b2f(v0.w >> 16);
      }
      __syncthreads();
    }
  }

  int c0 = (tt & 15)*8;
  #pragma unroll
  for (int j = 0; j < 8; j++) partial[sub*8 + h16][c0 + j] = acc[j];
  __syncthreads();
  if (t < 128){
    float s = 0.f;
    #pragma unroll
    for (int g = 0; g < 16; g++) s += partial[g][t];
    hout[(size_t)n*128 + t] = f2b(s*0.125f + bias[t]);
  }
}

// ---------------- pooling + fused head ----------------
__global__ void k_pool16(const unsigned short* __restrict__ h, const float* __restrict__ logit,
                         const int* __restrict__ gptr, float* __restrict__ pooled){
  int g = blockIdx.x, t = threadIdx.x;
  int beg = gptr[g], end = gptr[g+1];
  __shared__ float red[128];
  __shared__ float m_sh, s_sh;
  float mx = -1e30f;
  for (int i = beg + t; i < end; i += 128) mx = fmaxf(mx, logit[i]);
  red[t] = mx; __syncthreads();
  for (int off = 64; off > 0; off >>= 1){ if (t < off) red[t] = fmaxf(red[t], red[t + off]); __syncthreads(); }
  if (t == 0) m_sh = red[0];
  __syncthreads();
  float sm = 0.f;
  for (int i = beg + t; i < end; i += 128) sm += __expf(logit[i] - m_sh);
  red[t] = sm; __syncthreads();
  for (int off = 64; off > 0; off >>= 1){ if (t < off) red[t] += red[t + off]; __syncthreads(); }
  if (t == 0) s_sh = red[0] + 1e-16f;
  __syncthreads();
  float acc = 0.f;
  for (int i = beg; i < end; i++){
    float w = __expf(logit[i] - m_sh) / s_sh;
    acc += w * b2f(h[(size_t)i*128 + t]);
  }
  pooled[g*128 + t] = acc;
}

__global__ void k_head(const float* __restrict__ pooled,
                       const float* __restrict__ w1, const float* __restrict__ b1,
                       const float* __restrict__ w2, const float* __restrict__ b2,
                       float* __restrict__ out){
  int g = blockIdx.x, t = threadIdx.x;   // 128
  __shared__ float row[128];
  __shared__ float r0[128], r1[128];
  row[t] = pooled[g*128 + t];
  __syncthreads();
  float acc = b1[t];
  for (int k = 0; k < 128; k++) acc += row[k]*w1[k*128 + t];
  acc = fmaxf(acc, 0.f);
  r0[t] = acc*w2[t*2 + 0]; r1[t] = acc*w2[t*2 + 1];
  __syncthreads();
  for (int off = 64; off > 0; off >>= 1){
    if (t < off){ r0[t] += r0[t + off]; r1[t] += r1[t + off]; }
    __syncthreads();
  }
  if (t == 0){ out[g*2 + 0] = r0[0] + b2[0]; out[g*2 + 1] = r1[0] + b2[1]; }
}

extern "C" void kernel_launch(void* const* d_in, const int* in_sizes, int n_in,
                              void* d_out, int out_size, void* d_ws, size_t ws_size,
                              hipStream_t stream) {
  const float* x        = (const float*)d_in[0];
  const int*   ei       = (const int*)  d_in[1];
  const int*   batch    = (const int*)  d_in[2];
  const float* gw1[4] = {(const float*)d_in[3],  (const float*)d_in[7],  (const float*)d_in[11], (const float*)d_in[15]};
  const float* gb1[4] = {(const float*)d_in[4],  (const float*)d_in[8],  (const float*)d_in[12], (const float*)d_in[16]};
  const float* gw2[4] = {(const float*)d_in[5],  (const float*)d_in[9],  (const float*)d_in[13], (const float*)d_in[17]};
  const float* gb2[4] = {(const float*)d_in[6],  (const float*)d_in[10], (const float*)d_in[14], (const float*)d_in[18]};
  const float* bng[5] = {(const float*)d_in[19], (const float*)d_in[21], (const float*)d_in[23], (const float*)d_in[25], (const float*)d_in[27]};
  const float* bnb[5] = {(const float*)d_in[20], (const float*)d_in[22], (const float*)d_in[24], (const float*)d_in[26], (const float*)d_in[28]};
  const float* gat_w    = (const float*)d_in[29];
  const float* gat_asrc = (const float*)d_in[30];
  const float* gat_adst = (const float*)d_in[31];
  const float* gat_bias = (const float*)d_in[32];
  const float* gate_w   = (const float*)d_in[33];
  const float* gate_b   = (const float*)d_in[34];
  const float* fc1_w    = (const float*)d_in[35];
  const float* fc1_b    = (const float*)d_in[36];
  const float* fc2_w    = (const float*)d_in[37];
  const float* fc2_b    = (const float*)d_in[38];
  const int* src = ei;
  const int* dst = ei + NE;

  char* wsb = (char*)d_ws;
  size_t off = 0;
  auto take = [&](size_t bytes) -> void* {
    void* p = wsb + off;
    off = (off + bytes + 255) & ~(size_t)255;
    return p;
  };
  unsigned short* hpre  = (unsigned short*)take((size_t)NN*512*2);   // pre-BN bf16
  unsigned short* hb    = (unsigned short*)take((size_t)NN*512*2);   // post-BN bf16
  unsigned short* zh    = (unsigned short*)take((size_t)NN*1024*2);  // z16 | hid16; contiguous = xh16
  unsigned short* z16   = zh;
  unsigned short* hid16 = zh + (size_t)NN*512;
  unsigned short* xh16  = zh;
  unsigned short* xb    = (unsigned short*)take((size_t)NN*128*2);
  unsigned short* wt    = (unsigned short*)take((size_t)1000000*2);
  double* statsA = (double*)take(2560*8);
  float*  a_s    = (float*) take((size_t)NN*8*4);
  float*  a_d    = (float*) take((size_t)NN*8*4);
  float*  logit  = (float*) take((size_t)NN*4);
  float*  pooled = (float*) take((size_t)NG*128*4);
  int*    deg    = (int*)   take((size_t)NN*4);
  int*    cnt    = (int*)   take((size_t)NN*4);
  int*    gdeg   = (int*)   take((size_t)NG*4);
  int*    rowptr = (int*)   take((size_t)(NN+1)*4);
  int*    gptr   = (int*)   take((size_t)(NG+1)*4);
  int*    csrc   = (int*)   take((size_t)NE*4);
  (void)ws_size; (void)n_in; (void)in_sizes; (void)out_size;

  unsigned short* wt_g1w1 = wt;
  unsigned short* wt_g1w2 = wt_g1w1 + 128*128;
  unsigned short* wt_g2w1 = wt_g1w2 + 128*128;
  unsigned short* wt_g2w2 = wt_g2w1 + 256*128;
  unsigned short* wt_g3w1 = wt_g2w2 + 256*256;
  unsigned short* wt_g3w2 = wt_g3w1 + 512*256;
  unsigned short* wt_g4w1 = wt_g3w2 + 512*512;
  unsigned short* wt_g4w2 = wt_g4w1 + 256*512;
  unsigned short* wt_gat  = wt_g4w2 + 256*256;

  double* st1 = statsA + 0;     // d=128
  double* st2 = statsA + 256;   // d=256
  double* st3 = statsA + 768;   // d=512
  double* st4 = statsA + 1792;  // d=256
  double* st5 = statsA + 2304;  // d=128

  hipMemsetAsync(deg, 0, (size_t)((char*)(gdeg + NG) - (char*)deg), stream);
  hipMemsetAsync(statsA, 0, 2560*8, stream);

  k_hist2<<<(NE + NN + 255)/256, 256, 0, stream>>>(dst, batch, deg, gdeg);
  k_scan2<<<2, 1024, 0, stream>>>(deg, rowptr, gdeg, gptr);
  k_fill<<<(NE + 255)/256, 256, 0, stream>>>(src, dst, rowptr, cnt, csrc);

  // ---- coalesced weight prep ----
  {
    WPrep P;
    const float* Ws[9] = {gw1[0], gw2[0], gw1[1], gw2[1], gw1[2], gw2[2], gw1[3], gw2[3], gat_w};
    unsigned short* Wts[9] = {wt_g1w1, wt_g1w2, wt_g2w1, wt_g2w2, wt_g3w1, wt_g3w2, wt_g4w1, wt_g4w2, wt_gat};
    int Ks[9]  = {128, 128, 128, 256, 256, 512, 512, 256, 256};
    int Nns[9] = {128, 128, 256, 256, 512, 512, 256, 256, 1024};
    int cum = 0;
    for (int i = 0; i < 9; i++){
      P.W[i] = Ws[i]; P.Wt[i] = Wts[i]; P.K[i] = Ks[i]; P.Nn[i] = Nns[i];
      P.tileStart[i] = cum;
      cum += (Ks[i] >> 6)*(Nns[i] >> 6);
    }
    P.tileStart[9] = cum;                 // 240
    P.x = x; P.xb = (unsigned int*)xb;
    int xblocks = (NN*64 + 255)/256;      // 5000
    k_prep2<<<cum + xblocks, 256, 0, stream>>>(P);
  }

  const int GM = (NN + 127) / 128;

  auto bnTail = [&](int d, double* st, const float* g, const float* b, int gate){
    int total8 = NN*d/8;
    if (gate)
      k_bn_relu16<1><<<(total8 + 255)/256, 256, 0, stream>>>(hpre, hb, total8, d-1, d, st, g, b, gate_w, gate_b, logit);
    else
      k_bn_relu16<0><<<(total8 + 255)/256, 256, 0, stream>>>(hpre, hb, total8, d-1, d, st, g, b, nullptr, nullptr, nullptr);
  };

  // ---- GIN1: plain agg on x (d=128), then MLP (stats fused in w2) ----
  k_agg<0,64><<<NN/4, 256, 0, stream>>>((const unsigned int*)xb, rowptr, csrc, (unsigned int*)z16, nullptr, nullptr, nullptr, nullptr);
  k_gemm_mfma<1,1,0,0><<<dim3(1, GM), 256, 0, stream>>>(z16, wt_g1w1, gb1[0], nullptr, hid16, nullptr, nullptr, nullptr, nullptr, nullptr, NN, 128, 128);
  k_gemm_mfma<0,1,1,0><<<dim3(1, GM), 256, 0, stream>>>(hid16, wt_g1w2, gb2[0], nullptr, hpre, st1, nullptr, nullptr, nullptr, nullptr, NN, 128, 128);

  // ---- GIN2: BN1 fused into gather of hpre (d=128) ----
  k_agg<1,64><<<NN/4, 256, 0, stream>>>((const unsigned int*)hpre, rowptr, csrc, (unsigned int*)z16, st1, bng[0], bnb[0], nullptr);
  k_gemm_mfma<1,1,0,0><<<dim3(2, GM), 256, 0, stream>>>(z16, wt_g2w1, gb1[1], nullptr, hid16, nullptr, nullptr, nullptr, nullptr, nullptr, NN, 256, 128);
  k_gemm_mfma<0,1,1,0><<<dim3(2, GM), 256, 0, stream>>>(hid16, wt_g2w2, gb2[1], nullptr, hpre, st2, nullptr, nullptr, nullptr, nullptr, NN, 256, 256);

  // ---- GIN3: BN2 fused into gather of hpre (d=256) ----
  k_agg<1,128><<<NN/2, 256, 0, stream>>>((const unsigned int*)hpre, rowptr, csrc, (unsigned int*)z16, st2, bng[1], bnb[1], nullptr);
  k_gemm_mfma<1,1,0,0><<<dim3(4, GM), 256, 0, stream>>>(z16, wt_g3w1, gb1[2], nullptr, hid16, nullptr, nullptr, nullptr, nullptr, nullptr, NN, 512, 256);
  k_gemm_mfma<0,1,1,0><<<dim3(4, GM), 256, 0, stream>>>(hid16, wt_g3w2, gb2[2], nullptr, hpre, st3, nullptr, nullptr, nullptr, nullptr, NN, 512, 512);
  bnTail(512, st3, bng[2], bnb[2], 0);

  // ---- GIN4: w1 first (512->256), agg post-w1 with bias+relu, then w2 ----
  k_gemm_mfma<0,1,0,0><<<dim3(2, GM), 256, 0, stream>>>(hb, wt_g4w1, nullptr, nullptr, hid16, nullptr, nullptr, nullptr, nullptr, nullptr, NN, 256, 512);
  k_agg<2,128><<<NN/2, 256, 0, stream>>>((const unsigned int*)hid16, rowptr, csrc, (unsigned int*)z16, nullptr, nullptr, nullptr, gb1[3]);
  k_gemm_mfma<0,1,1,0><<<dim3(2, GM), 256, 0, stream>>>(z16, wt_g4w2, gb2[3], nullptr, hpre, st4, nullptr, nullptr, nullptr, nullptr, NN, 256, 256);
  bnTail(256, st4, bng[3], bnb[3], 0);

  // ---- GAT (scores fused into GEMM epilogue) ----
  k_gemm_mfma<0,1,0,1><<<dim3(8, GM), 256, 0, stream>>>(hb, wt_gat, nullptr, nullptr, xh16, nullptr, gat_asrc, gat_adst, a_s, a_d, NN, 1024, 256);
  k_gat_node256<<<NN, 256, 0, stream>>>(xh16, a_s, a_d, rowptr, csrc, gat_bias, hpre);
  k_bn_stats16<<<(NN + 63)/64, 128, 0, stream>>>(hpre, 128, st5);
  bnTail(128, st5, bng[4], bnb[4], 1);

  // ---- pooling + head ----
  k_pool16<<<NG, 128, 0, stream>>>(hb, logit, gptr, pooled);
  k_head<<<NG, 128, 0, stream>>>(pooled, fc1_w, fc1_b, fc2_w, fc2_b, (float*)d_out);
}

// Round 6
// 600.975 us; speedup vs baseline: 1.0671x; 1.0671x over previous
//
#include <hip/hip_runtime.h>
#include <hip/hip_bf16.h>
#include <math.h>

#define NN 20000
#define NE 320000
#define NG 128

using bf16x8 = __attribute__((ext_vector_type(8))) short;
using f32x4  = __attribute__((ext_vector_type(4))) float;

static __device__ __forceinline__ float lrelu(float v){ return v > 0.f ? v : 0.2f*v; }
static __device__ __forceinline__ float b2f(unsigned short u){ unsigned int v = ((unsigned int)u) << 16; return __uint_as_float(v); }
static __device__ __forceinline__ unsigned short f2b(float f){
  unsigned int x = __float_as_uint(f);
  unsigned int r = x + 0x7fffu + ((x >> 16) & 1u);
  return (unsigned short)(r >> 16);
}
static __device__ __forceinline__ void gl16(const unsigned short* g, unsigned short* l){
  __builtin_amdgcn_global_load_lds((const __attribute__((address_space(1))) void*)g,
                                   (__attribute__((address_space(3))) void*)l, 16, 0, 0);
}
// apply bnrelu to 8 packed bf16 with features f0..f0+7
static __device__ __forceinline__ uint4 bn8(uint4 u, const float* scs, const float* shs, int f0){
  float v[8] = { b2f(u.x & 0xffff), b2f(u.x >> 16), b2f(u.y & 0xffff), b2f(u.y >> 16),
                 b2f(u.z & 0xffff), b2f(u.z >> 16), b2f(u.w & 0xffff), b2f(u.w >> 16) };
  #pragma unroll
  for (int j = 0; j < 8; j++) v[j] = fmaxf(v[j]*scs[f0 + j] + shs[f0 + j], 0.f);
  uint4 p;
  p.x = (unsigned int)f2b(v[0]) | ((unsigned int)f2b(v[1]) << 16);
  p.y = (unsigned int)f2b(v[2]) | ((unsigned int)f2b(v[3]) << 16);
  p.z = (unsigned int)f2b(v[4]) | ((unsigned int)f2b(v[5]) << 16);
  p.w = (unsigned int)f2b(v[6]) | ((unsigned int)f2b(v[7]) << 16);
  return p;
}

// ---------------- CSR build ----------------
__global__ void k_hist2(const int* __restrict__ dst, const int* __restrict__ batch,
                        int* __restrict__ deg, int* __restrict__ gdeg){
  int i = blockIdx.x*blockDim.x + threadIdx.x;
  if (i < NE) atomicAdd(&deg[dst[i]], 1);
  else if (i < NE + NN) atomicAdd(&gdeg[batch[i - NE]], 1);
}

// fast scan: thread-local 20-element runs + one 1024-wide barrier scan
__global__ void k_scan2(const int* __restrict__ deg, int* __restrict__ rowptr,
                        const int* __restrict__ gdeg, int* __restrict__ gptr){
  __shared__ int tmp[1024];
  int t = threadIdx.x;
  if (blockIdx.x == 0){
    const int CH = 20;                      // 1024*20 >= NN
    int lo = t*CH, hi = min(lo + CH, NN);
    int loc[CH];
    int s = 0;
    for (int i = lo; i < hi; i++){ loc[i - lo] = deg[i]; s += loc[i - lo]; }
    tmp[t] = s; __syncthreads();
    for (int off = 1; off < 1024; off <<= 1){
      int u = (t >= off) ? tmp[t - off] : 0;
      __syncthreads();
      tmp[t] += u;
      __syncthreads();
    }
    int r = tmp[t] - s;                     // exclusive prefix
    if (t == 0) rowptr[0] = 0;
    for (int i = lo; i < hi; i++){ r += loc[i - lo]; rowptr[i + 1] = r; }
  } else {
    int v = (t < NG) ? gdeg[t] : 0;
    tmp[t] = v; __syncthreads();
    for (int off = 1; off < 1024; off <<= 1){
      int u = (t >= off) ? tmp[t - off] : 0;
      __syncthreads();
      tmp[t] += u;
      __syncthreads();
    }
    if (t == 0) gptr[0] = 0;
    if (t < NG) gptr[t + 1] = tmp[t];
  }
}

__global__ void k_fill(const int* __restrict__ src, const int* __restrict__ dst,
                       const int* __restrict__ ptr, int* __restrict__ cnt,
                       int* __restrict__ csrc){
  int e = blockIdx.x*blockDim.x + threadIdx.x;
  if (e < NE){
    int d = dst[e];
    int p = atomicAdd(&cnt[d], 1);
    csrc[ptr[d] + p] = src[e];
  }
}

// ---------------- weight prep: coalesced 64x64 tile transpose + x cast ----------------
struct WPrep {
  const float* W[9];
  unsigned short* Wt[9];
  int K[9];
  int Nn[9];
  int tileStart[10];
  const float* x;
  unsigned int* xb;
};

__global__ __launch_bounds__(256)
void k_prep2(WPrep P){
  __shared__ float tile[64][65];
  int b = blockIdx.x;
  if (b < P.tileStart[9]){
    int i = 0;
    while (i < 8 && b >= P.tileStart[i+1]) i++;
    int ti = b - P.tileStart[i];
    int K = P.K[i], Nn = P.Nn[i];
    int ntc = Nn >> 6;
    int k0 = (ti / ntc) << 6, n0 = (ti % ntc) << 6;
    int c = threadIdx.x & 63, ro = threadIdx.x >> 6;
    const float* W = P.W[i];
    #pragma unroll
    for (int rr = 0; rr < 16; rr++){
      int r = rr*4 + ro;
      tile[c][r] = W[(size_t)(k0 + r)*Nn + n0 + c];
    }
    __syncthreads();
    unsigned short* Wt = P.Wt[i];
    #pragma unroll
    for (int cc = 0; cc < 16; cc++){
      int cidx = cc*4 + ro;
      Wt[(size_t)(n0 + cidx)*K + k0 + c] = f2b(tile[cidx][c]);
    }
  } else {
    int idx = (b - P.tileStart[9])*256 + threadIdx.x;
    if (idx < NN*64){
      unsigned int lo = f2b(P.x[2*idx]);
      unsigned int hi = f2b(P.x[2*idx + 1]);
      P.xb[idx] = lo | (hi << 16);
    }
  }
}

// ---------------- unified GIN aggregation (unroll-8) ----------------
// MODE 0: z = self + sum(nb)    MODE 1: z = bnrelu(self)+sum bnrelu(nb)   MODE 2: z = relu(agg+bias)
template<int MODE, int DU>
__global__ __launch_bounds__(256)
void k_agg(const unsigned int* __restrict__ hU, const int* __restrict__ ptr,
           const int* __restrict__ csrc, unsigned int* __restrict__ z,
           const double* __restrict__ stats, const float* __restrict__ g,
           const float* __restrict__ bb, const float* __restrict__ bias){
  const int d = DU*2;
  __shared__ float scs[MODE == 1 ? 512 : 1];
  __shared__ float shs[MODE == 1 ? 512 : 1];
  int t = threadIdx.x;
  if (MODE == 1){
    for (int f = t; f < d; f += 256){
      double inv = 1.0 / (double)NN;
      double mu  = stats[f]*inv;
      double var = stats[d + f]*inv - mu*mu;
      if (var < 0.0) var = 0.0;
      float sc = g[f] * rsqrtf((float)var + 1e-5f);
      scs[f] = sc;
      shs[f] = bb[f] - (float)mu*sc;
    }
    __syncthreads();
  }
  const int npb = 256/DU;
  int n  = blockIdx.x*npb + t/DU;
  int tl = t & (DU - 1);
  int f0 = 2*tl, f1 = f0 + 1;
  float sc0 = 0.f, sh0 = 0.f, sc1 = 0.f, sh1 = 0.f;
  if (MODE == 1){ sc0 = scs[f0]; sh0 = shs[f0]; sc1 = scs[f1]; sh1 = shs[f1]; }
  int beg = ptr[n], deg = ptr[n+1] - beg;
  unsigned int self = hU[(size_t)n*DU + tl];
  float a0, a1;
  if (MODE == 1){
    a0 = fmaxf(b2f(self & 0xffff)*sc0 + sh0, 0.f);
    a1 = fmaxf(b2f(self >> 16)   *sc1 + sh1, 0.f);
  } else {
    a0 = b2f(self & 0xffff);
    a1 = b2f(self >> 16);
  }
  int i = 0;
  for (; i + 8 <= deg; i += 8){
    unsigned int v[8];
    #pragma unroll
    for (int u = 0; u < 8; u++) v[u] = hU[(size_t)csrc[beg + i + u]*DU + tl];
    #pragma unroll
    for (int u = 0; u < 8; u++){
      if (MODE == 1){
        a0 += fmaxf(b2f(v[u] & 0xffff)*sc0 + sh0, 0.f);
        a1 += fmaxf(b2f(v[u] >> 16)   *sc1 + sh1, 0.f);
      } else {
        a0 += b2f(v[u] & 0xffff);
        a1 += b2f(v[u] >> 16);
      }
    }
  }
  for (; i < deg; i++){
    unsigned int v = hU[(size_t)csrc[beg + i]*DU + tl];
    if (MODE == 1){
      a0 += fmaxf(b2f(v & 0xffff)*sc0 + sh0, 0.f);
      a1 += fmaxf(b2f(v >> 16)   *sc1 + sh1, 0.f);
    } else {
      a0 += b2f(v & 0xffff);
      a1 += b2f(v >> 16);
    }
  }
  if (MODE == 2){
    a0 = fmaxf(a0 + bias[f0], 0.f);
    a1 = fmaxf(a1 + bias[f1], 0.f);
  }
  z[(size_t)n*DU + tl] = (unsigned int)f2b(a0) | ((unsigned int)f2b(a1) << 16);
}

// ---------------- bf16 MFMA GEMM ----------------
// BNA=1: A is pre-BN bf16; bnrelu applied during reg-staging (padded LDS).
template<int ACT, int OBF, int STATS, int SCORES, int BNA>
__global__ __launch_bounds__(256)
void k_gemm_mfma(const unsigned short* __restrict__ A, const unsigned short* __restrict__ Bt,
                 const float* __restrict__ bias, float* __restrict__ C,
                 unsigned short* __restrict__ Cb, double* __restrict__ stats,
                 const float* __restrict__ asrc, const float* __restrict__ adst,
                 float* __restrict__ a_s, float* __restrict__ a_d,
                 const double* __restrict__ bnst, const float* __restrict__ bng,
                 const float* __restrict__ bnb,
                 int M, int Nn, int K){
  const int LDA = BNA ? 40 : 32;
  __shared__ unsigned short As[2][128*(BNA ? 40 : 32)];
  __shared__ unsigned short Bs[2][128*32];
  __shared__ float sS[SCORES ? 128 : 1];
  __shared__ float sD[SCORES ? 128 : 1];
  __shared__ float scs[BNA ? 512 : 1];
  __shared__ float shs[BNA ? 512 : 1];
  const int bm = blockIdx.y*128, bn = blockIdx.x*128;
  const int tid = threadIdx.x;
  const int lane = tid & 63;
  const int wave = tid >> 6;
  const int wm = (wave >> 1)*64, wn = (wave & 1)*64;
  const int lr = lane & 15, lq = lane >> 4;

  f32x4 acc[4][4];
  #pragma unroll
  for (int i = 0; i < 4; i++)
    #pragma unroll
    for (int j = 0; j < 4; j++) acc[i][j] = (f32x4){0.f,0.f,0.f,0.f};

  const int rowA = tid >> 2, q = tid & 3;
  const int ldsOff = wave*16*32;
  const int gmA0 = min(bm + rowA,      M-1);
  const int gmA1 = min(bm + rowA + 64, M-1);
  const unsigned short* pA0 = &A[(size_t)gmA0*K + q*8];
  const unsigned short* pA1 = &A[(size_t)gmA1*K + q*8];
  const unsigned short* pB0 = &Bt[(size_t)(bn + rowA)*K + q*8];
  const unsigned short* pB1 = &Bt[(size_t)(bn + rowA + 64)*K + q*8];

  if (BNA){
    for (int f = tid; f < K; f += 256){
      double inv = 1.0 / (double)NN;
      double mu  = bnst[f]*inv;
      double var = bnst[K + f]*inv - mu*mu;
      if (var < 0.0) var = 0.0;
      float sc = bng[f] * rsqrtf((float)var + 1e-5f);
      scs[f] = sc;
      shs[f] = bnb[f] - (float)mu*sc;
    }
    __syncthreads();
  }

  // prologue stage (buffer 0)
  if (BNA){
    uint4 u0 = *(const uint4*)pA0;
    uint4 u1 = *(const uint4*)pA1;
    int f0 = q*8;
    *(uint4*)&As[0][ rowA      *LDA + q*8] = bn8(u0, scs, shs, f0);
    *(uint4*)&As[0][(rowA + 64)*LDA + q*8] = bn8(u1, scs, shs, f0);
  } else {
    gl16(pA0, &As[0][ldsOff]);
    gl16(pA1, &As[0][ldsOff] + 64*32);
  }
  gl16(pB0, &Bs[0][ldsOff]);
  gl16(pB1, &Bs[0][ldsOff] + 64*32);
  __syncthreads();

  int cur = 0;
  for (int k0 = 0; k0 < K; k0 += 32){
    const int kn = k0 + 32;
    uint4 nu0, nu1;
    if (kn < K){
      if (BNA){
        nu0 = *(const uint4*)(pA0 + kn);
        nu1 = *(const uint4*)(pA1 + kn);
      } else {
        gl16(pA0 + kn, &As[cur^1][ldsOff]);
        gl16(pA1 + kn, &As[cur^1][ldsOff] + 64*32);
      }
      gl16(pB0 + kn, &Bs[cur^1][ldsOff]);
      gl16(pB1 + kn, &Bs[cur^1][ldsOff] + 64*32);
    }
    bf16x8 af[4], bf[4];
    #pragma unroll
    for (int mi = 0; mi < 4; mi++)
      af[mi] = *(const bf16x8*)&As[cur][(wm + mi*16 + lr)*LDA + lq*8];
    #pragma unroll
    for (int ni = 0; ni < 4; ni++)
      bf[ni] = *(const bf16x8*)&Bs[cur][(wn + ni*16 + lr)*32 + lq*8];
    #pragma unroll
    for (int mi = 0; mi < 4; mi++)
      #pragma unroll
      for (int ni = 0; ni < 4; ni++)
        acc[mi][ni] = __builtin_amdgcn_mfma_f32_16x16x32_bf16(af[mi], bf[ni], acc[mi][ni], 0, 0, 0);
    if (BNA && kn < K){
      int f0 = kn + q*8;
      *(uint4*)&As[cur^1][ rowA      *LDA + q*8] = bn8(nu0, scs, shs, f0);
      *(uint4*)&As[cur^1][(rowA + 64)*LDA + q*8] = bn8(nu1, scs, shs, f0);
    }
    __syncthreads();
    cur ^= 1;
  }

  float cs[4] = {0.f,0.f,0.f,0.f}, cq[4] = {0.f,0.f,0.f,0.f};
  #pragma unroll
  for (int mi = 0; mi < 4; mi++){
    #pragma unroll
    for (int j = 0; j < 4; j++){
      int gm = bm + wm + mi*16 + lq*4 + j;
      if (gm < M){
        #pragma unroll
        for (int ni = 0; ni < 4; ni++){
          int gn = bn + wn + ni*16 + lr;
          float v = acc[mi][ni][j] + (bias ? bias[gn] : 0.f);
          if (ACT) v = fmaxf(v, 0.f);
          if (OBF) Cb[(size_t)gm*Nn + gn] = f2b(v);
          else     C [(size_t)gm*Nn + gn] = v;
          if (STATS){ cs[ni] += v; cq[ni] += v*v; }
        }
      }
    }
  }
  if (STATS){
    #pragma unroll
    for (int ni = 0; ni < 4; ni++){
      float s = cs[ni], qq = cq[ni];
      s += __shfl_xor(s, 16); s += __shfl_xor(s, 32);
      qq += __shfl_xor(qq, 16); qq += __shfl_xor(qq, 32);
      if (lane < 16){
        int gn = bn + wn + ni*16 + lr;
        atomicAdd(&stats[gn],      (double)s);
        atomicAdd(&stats[Nn + gn], (double)qq);
      }
    }
  }
  if (SCORES){
    const int hd = bn >> 7;
    float av[4], dv[4];
    #pragma unroll
    for (int ni = 0; ni < 4; ni++){
      int c = wn + ni*16 + lr;
      av[ni] = asrc[hd*128 + c];
      dv[ni] = adst[hd*128 + c];
    }
    float psS[4][4], psD[4][4];
    #pragma unroll
    for (int mi = 0; mi < 4; mi++)
      #pragma unroll
      for (int j = 0; j < 4; j++){
        float s = 0.f, d2 = 0.f;
        #pragma unroll
        for (int ni = 0; ni < 4; ni++){
          float v = acc[mi][ni][j];
          s  += v*av[ni];
          d2 += v*dv[ni];
        }
        #pragma unroll
        for (int o = 1; o < 16; o <<= 1){ s += __shfl_xor(s, o); d2 += __shfl_xor(d2, o); }
        psS[mi][j] = s; psD[mi][j] = d2;
      }
    if (wn == 0 && lr == 0){
      #pragma unroll
      for (int mi = 0; mi < 4; mi++)
        #pragma unroll
        for (int j = 0; j < 4; j++){
          int r = wm + mi*16 + lq*4 + j;
          sS[r] = psS[mi][j]; sD[r] = psD[mi][j];
        }
    }
    __syncthreads();
    if (wn != 0 && lr == 0){
      #pragma unroll
      for (int mi = 0; mi < 4; mi++)
        #pragma unroll
        for (int j = 0; j < 4; j++){
          int r = wm + mi*16 + lq*4 + j;
          sS[r] += psS[mi][j]; sD[r] += psD[mi][j];
        }
    }
    __syncthreads();
    if (tid < 128){
      int gm = bm + tid;
      if (gm < M){ a_s[gm*8 + hd] = sS[tid]; a_d[gm*8 + hd] = sD[tid]; }
    }
  }
}

// ---------------- fused GIN1 MLP: Out = (relu(Z@W1+b1))@W2 + b2, hid kept in LDS ----------------
__global__ __launch_bounds__(256)
void k_gin1_mlp(const unsigned short* __restrict__ Z, const unsigned short* __restrict__ W1t,
                const float* __restrict__ b1, const unsigned short* __restrict__ W2t,
                const float* __restrict__ b2, unsigned short* __restrict__ Out,
                double* __restrict__ stats, int M){
  __shared__ unsigned short As[2][128*32];
  __shared__ unsigned short Bs[2][128*32];
  __shared__ unsigned short hid[128*136];
  const int bm = blockIdx.x*128;
  const int tid = threadIdx.x;
  const int lane = tid & 63;
  const int wave = tid >> 6;
  const int wm = (wave >> 1)*64, wn = (wave & 1)*64;
  const int lr = lane & 15, lq = lane >> 4;
  const int rowA = tid >> 2, q = tid & 3;
  const int ldsOff = wave*16*32;
  const int gm0 = min(bm + rowA,      M-1);
  const int gm1 = min(bm + rowA + 64, M-1);
  const unsigned short* pA0 = &Z[(size_t)gm0*128 + q*8];
  const unsigned short* pA1 = &Z[(size_t)gm1*128 + q*8];
  const unsigned short* pB0 = &W1t[(size_t)rowA*128 + q*8];
  const unsigned short* pB1 = &W1t[(size_t)(rowA + 64)*128 + q*8];

  f32x4 acc[4][4];
  #pragma unroll
  for (int i = 0; i < 4; i++)
    #pragma unroll
    for (int j = 0; j < 4; j++) acc[i][j] = (f32x4){0.f,0.f,0.f,0.f};

  // ---- phase 1: hid = relu(Z@W1 + b1) ----
  gl16(pA0, &As[0][ldsOff]);
  gl16(pA1, &As[0][ldsOff] + 64*32);
  gl16(pB0, &Bs[0][ldsOff]);
  gl16(pB1, &Bs[0][ldsOff] + 64*32);
  __syncthreads();
  int cur = 0;
  for (int k0 = 0; k0 < 128; k0 += 32){
    int kn = k0 + 32;
    if (kn < 128){
      gl16(pA0 + kn, &As[cur^1][ldsOff]);
      gl16(pA1 + kn, &As[cur^1][ldsOff] + 64*32);
      gl16(pB0 + kn, &Bs[cur^1][ldsOff]);
      gl16(pB1 + kn, &Bs[cur^1][ldsOff] + 64*32);
    }
    bf16x8 af[4], bf[4];
    #pragma unroll
    for (int mi = 0; mi < 4; mi++)
      af[mi] = *(const bf16x8*)&As[cur][(wm + mi*16 + lr)*32 + lq*8];
    #pragma unroll
    for (int ni = 0; ni < 4; ni++)
      bf[ni] = *(const bf16x8*)&Bs[cur][(wn + ni*16 + lr)*32 + lq*8];
    #pragma unroll
    for (int mi = 0; mi < 4; mi++)
      #pragma unroll
      for (int ni = 0; ni < 4; ni++)
        acc[mi][ni] = __builtin_amdgcn_mfma_f32_16x16x32_bf16(af[mi], bf[ni], acc[mi][ni], 0, 0, 0);
    __syncthreads();
    cur ^= 1;
  }
  {
    float bv[4];
    #pragma unroll
    for (int ni = 0; ni < 4; ni++) bv[ni] = b1[wn + ni*16 + lr];
    #pragma unroll
    for (int mi = 0; mi < 4; mi++)
      #pragma unroll
      for (int j = 0; j < 4; j++){
        int row = wm + mi*16 + lq*4 + j;
        #pragma unroll
        for (int ni = 0; ni < 4; ni++){
          int col = wn + ni*16 + lr;
          hid[row*136 + col] = f2b(fmaxf(acc[mi][ni][j] + bv[ni], 0.f));
        }
      }
  }
  __syncthreads();

  // ---- phase 2: Out = hid@W2 + b2 (+stats) ----
  f32x4 acc2[4][4];
  #pragma unroll
  for (int i = 0; i < 4; i++)
    #pragma unroll
    for (int j = 0; j < 4; j++) acc2[i][j] = (f32x4){0.f,0.f,0.f,0.f};
  const unsigned short* pC0 = &W2t[(size_t)rowA*128 + q*8];
  const unsigned short* pC1 = &W2t[(size_t)(rowA + 64)*128 + q*8];
  gl16(pC0, &Bs[0][ldsOff]);
  gl16(pC1, &Bs[0][ldsOff] + 64*32);
  __syncthreads();
  cur = 0;
  for (int k0 = 0; k0 < 128; k0 += 32){
    int kn = k0 + 32;
    if (kn < 128){
      gl16(pC0 + kn, &Bs[cur^1][ldsOff]);
      gl16(pC1 + kn, &Bs[cur^1][ldsOff] + 64*32);
    }
    bf16x8 af[4], bf[4];
    #pragma unroll
    for (int mi = 0; mi < 4; mi++)
      af[mi] = *(const bf16x8*)&hid[(wm + mi*16 + lr)*136 + k0 + lq*8];
    #pragma unroll
    for (int ni = 0; ni < 4; ni++)
      bf[ni] = *(const bf16x8*)&Bs[cur][(wn + ni*16 + lr)*32 + lq*8];
    #pragma unroll
    for (int mi = 0; mi < 4; mi++)
      #pragma unroll
      for (int ni = 0; ni < 4; ni++)
        acc2[mi][ni] = __builtin_amdgcn_mfma_f32_16x16x32_bf16(af[mi], bf[ni], acc2[mi][ni], 0, 0, 0);
    __syncthreads();
    cur ^= 1;
  }
  float cs[4] = {0.f,0.f,0.f,0.f}, cq[4] = {0.f,0.f,0.f,0.f};
  #pragma unroll
  for (int mi = 0; mi < 4; mi++){
    #pragma unroll
    for (int j = 0; j < 4; j++){
      int gm = bm + wm + mi*16 + lq*4 + j;
      if (gm < M){
        #pragma unroll
        for (int ni = 0; ni < 4; ni++){
          int gn = wn + ni*16 + lr;
          float v = acc2[mi][ni][j] + b2[gn];
          Out[(size_t)gm*128 + gn] = f2b(v);
          cs[ni] += v; cq[ni] += v*v;
        }
      }
    }
  }
  #pragma unroll
  for (int ni = 0; ni < 4; ni++){
    float s = cs[ni], qq = cq[ni];
    s += __shfl_xor(s, 16); s += __shfl_xor(s, 32);
    qq += __shfl_xor(qq, 16); qq += __shfl_xor(qq, 32);
    if (lane < 16){
      int gn = wn + ni*16 + lr;
      atomicAdd(&stats[gn],       (double)s);
      atomicAdd(&stats[128 + gn], (double)qq);
    }
  }
}

// ---------------- BatchNorm (bn5 only) ----------------
__global__ void k_bn_stats16(const unsigned short* __restrict__ h, int d, double* __restrict__ stats){
  int r0 = blockIdx.x*64;
  int rend = min(NN, r0 + 64);
  for (int f = threadIdx.x; f < d; f += blockDim.x){
    float s = 0.f, q = 0.f;
    for (int r = r0; r < rend; r++){ float v = b2f(h[(size_t)r*d + f]); s += v; q += v*v; }
    atomicAdd(&stats[f], (double)s);
    atomicAdd(&stats[d + f], (double)q);
  }
}

__global__ __launch_bounds__(256)
void k_bn_relu_gate(const unsigned short* __restrict__ hpre, unsigned short* __restrict__ hb,
                    int total8, const double* __restrict__ stats,
                    const float* __restrict__ g, const float* __restrict__ b,
                    const float* __restrict__ gatew, const float* __restrict__ gateb,
                    float* __restrict__ logit){
  const int d = 128;
  __shared__ float scs[128], shs[128];
  for (int f = threadIdx.x; f < d; f += blockDim.x){
    double inv = 1.0 / (double)NN;
    double mu  = stats[f]*inv;
    double var = stats[d + f]*inv - mu*mu;
    if (var < 0.0) var = 0.0;
    float sc = g[f] * rsqrtf((float)var + 1e-5f);
    scs[f] = sc;
    shs[f] = b[f] - (float)mu*sc;
  }
  __syncthreads();
  int i = blockIdx.x*blockDim.x + threadIdx.x;
  if (i >= total8) return;
  int i8 = i*8;
  uint4 u = *(const uint4*)&hpre[i8];
  float v[8] = { b2f(u.x & 0xffff), b2f(u.x >> 16), b2f(u.y & 0xffff), b2f(u.y >> 16),
                 b2f(u.z & 0xffff), b2f(u.z >> 16), b2f(u.w & 0xffff), b2f(u.w >> 16) };
  int f0 = i8 & 127;
  float gp = 0.f;
  #pragma unroll
  for (int j = 0; j < 8; j++){
    float y = fmaxf(v[j]*scs[f0 + j] + shs[f0 + j], 0.f);
    v[j] = y;
    gp += y*gatew[f0 + j];
  }
  uint4 p;
  p.x = (unsigned int)f2b(v[0]) | ((unsigned int)f2b(v[1]) << 16);
  p.y = (unsigned int)f2b(v[2]) | ((unsigned int)f2b(v[3]) << 16);
  p.z = (unsigned int)f2b(v[4]) | ((unsigned int)f2b(v[5]) << 16);
  p.w = (unsigned int)f2b(v[6]) | ((unsigned int)f2b(v[7]) << 16);
  *(uint4*)&hb[i8] = p;
  #pragma unroll
  for (int o = 1; o < 16; o <<= 1) gp += __shfl_xor(gp, o);
  if ((threadIdx.x & 15) == 0) logit[i >> 4] = gp + gateb[0];
}

// ---------------- GAT node aggregate (writes bf16) ----------------
__global__ __launch_bounds__(256)
void k_gat_node256(const unsigned short* __restrict__ xh, const float* __restrict__ a_s,
                   const float* __restrict__ a_d, const int* __restrict__ ptr,
                   const int* __restrict__ csrc, const float* __restrict__ bias,
                   unsigned short* __restrict__ hout){
  int n = blockIdx.x, t = threadIdx.x;
  int beg = ptr[n], deg = ptr[n+1] - beg;
  int tot = deg + 1;
  __shared__ float elv[256][9];
  __shared__ int esrc[256];
  __shared__ float red[256];
  __shared__ float ms[8], ssinv[8], adn[8];
  __shared__ float partial[16][132];
  if (t < 8) adn[t] = a_d[n*8 + t];
  __syncthreads();
  int head = t >> 5, slot = t & 31;
  int sub = t >> 7, tt = t & 127;
  int h16 = tt >> 4;
  float acc[8] = {0.f,0.f,0.f,0.f,0.f,0.f,0.f,0.f};

  if (tot <= 256){
    for (int i = t; i < tot; i += 256) esrc[i] = (i < deg) ? csrc[beg + i] : n;
    __syncthreads();
    for (int i = t; i < tot*8; i += 256){
      int le = i >> 3, hh = i & 7;
      elv[le][hh] = lrelu(a_s[esrc[le]*8 + hh] + adn[hh]);
    }
    __syncthreads();
    float mx = -1e30f;
    for (int e = slot; e < tot; e += 32) mx = fmaxf(mx, elv[e][head]);
    red[t] = mx; __syncthreads();
    #pragma unroll
    for (int off = 16; off >= 1; off >>= 1){
      if (slot < off) red[t] = fmaxf(red[t], red[t + off]);
      __syncthreads();
    }
    if (slot == 0) ms[head] = red[t];
    __syncthreads();
    float sm = 0.f;
    for (int e = slot; e < tot; e += 32){
      float ex = __expf(elv[e][head] - ms[head]);
      elv[e][head] = ex;
      sm += ex;
    }
    red[t] = sm; __syncthreads();
    #pragma unroll
    for (int off = 16; off >= 1; off >>= 1){
      if (slot < off) red[t] += red[t + off];
      __syncthreads();
    }
    if (slot == 0) ssinv[head] = 1.f / (red[t] + 1e-16f);
    __syncthreads();
    int lo = sub*128, hi = min(tot, lo + 128);
    float si = ssinv[h16];
    int i = lo;
    for (; i + 2 <= hi; i += 2){
      const uint4* r0 = (const uint4*)(xh + (size_t)esrc[i]*1024);
      const uint4* r1 = (const uint4*)(xh + (size_t)esrc[i+1]*1024);
      uint4 v0 = r0[tt], v1 = r1[tt];
      float a0 = elv[i][h16]*si, a1 = elv[i+1][h16]*si;
      acc[0] += a0*b2f(v0.x & 0xffff) + a1*b2f(v1.x & 0xffff);
      acc[1] += a0*b2f(v0.x >> 16)    + a1*b2f(v1.x >> 16);
      acc[2] += a0*b2f(v0.y & 0xffff) + a1*b2f(v1.y & 0xffff);
      acc[3] += a0*b2f(v0.y >> 16)    + a1*b2f(v1.y >> 16);
      acc[4] += a0*b2f(v0.z & 0xffff) + a1*b2f(v1.z & 0xffff);
      acc[5] += a0*b2f(v0.z >> 16)    + a1*b2f(v1.z >> 16);
      acc[6] += a0*b2f(v0.w & 0xffff) + a1*b2f(v1.w & 0xffff);
      acc[7] += a0*b2f(v0.w >> 16)    + a1*b2f(v1.w >> 16);
    }
    for (; i < hi; i++){
      const uint4* r0 = (const uint4*)(xh + (size_t)esrc[i]*1024);
      uint4 v0 = r0[tt];
      float a0 = elv[i][h16]*si;
      acc[0] += a0*b2f(v0.x & 0xffff); acc[1] += a0*b2f(v0.x >> 16);
      acc[2] += a0*b2f(v0.y & 0xffff); acc[3] += a0*b2f(v0.y >> 16);
      acc[4] += a0*b2f(v0.z & 0xffff); acc[5] += a0*b2f(v0.z >> 16);
      acc[6] += a0*b2f(v0.w & 0xffff); acc[7] += a0*b2f(v0.w >> 16);
    }
    __syncthreads();
  } else {
    float mx = -1e30f;
    for (int e = slot; e < tot; e += 32){
      int s = (e < deg) ? csrc[beg + e] : n;
      mx = fmaxf(mx, lrelu(a_s[s*8 + head] + adn[head]));
    }
    red[t] = mx; __syncthreads();
    #pragma unroll
    for (int off = 16; off >= 1; off >>= 1){
      if (slot < off) red[t] = fmaxf(red[t], red[t + off]);
      __syncthreads();
    }
    if (slot == 0) ms[head] = red[t];
    __syncthreads();
    float sm = 0.f;
    for (int e = slot; e < tot; e += 32){
      int s = (e < deg) ? csrc[beg + e] : n;
      sm += __expf(lrelu(a_s[s*8 + head] + adn[head]) - ms[head]);
    }
    red[t] = sm; __syncthreads();
    #pragma unroll
    for (int off = 16; off >= 1; off >>= 1){
      if (slot < off) red[t] += red[t + off];
      __syncthreads();
    }
    if (slot == 0) ssinv[head] = 1.f / (red[t] + 1e-16f);
    __syncthreads();
    float si = ssinv[h16];
    for (int ch = 0; ch < tot; ch += 256){
      int ce = min(256, tot - ch);
      for (int i = t; i < ce*8; i += 256){
        int le = i >> 3, hh = i & 7;
        int s = (ch + le < deg) ? csrc[beg + ch + le] : n;
        if (hh == 0) esrc[le] = s;
        elv[le][hh] = __expf(lrelu(a_s[s*8 + hh] + adn[hh]) - ms[hh]);
      }
      __syncthreads();
      int lo = sub*128, hi = min(ce, lo + 128);
      for (int i = lo; i < hi; i++){
        const uint4* r0 = (const uint4*)(xh + (size_t)esrc[i]*1024);
        uint4 v0 = r0[tt];
        float a0 = elv[i][h16]*si;
        acc[0] += a0*b2f(v0.x & 0xffff); acc[1] += a0*b2f(v0.x >> 16);
        acc[2] += a0*b2f(v0.y & 0xffff); acc[3] += a0*b2f(v0.y >> 16);
        acc[4] += a0*b2f(v0.z & 0xffff); acc[5] += a0*b2f(v0.z >> 16);
        acc[6] += a0*b2f(v0.w & 0xffff); acc[7] += a0*b2f(v0.w >> 16);
      }
      __syncthreads();
    }
  }

  int c0 = (tt & 15)*8;
  #pragma unroll
  for (int j = 0; j < 8; j++) partial[sub*8 + h16][c0 + j] = acc[j];
  __syncthreads();
  if (t < 128){
    float s = 0.f;
    #pragma unroll
    for (int g = 0; g < 16; g++) s += partial[g][t];
    hout[(size_t)n*128 + t] = f2b(s*0.125f + bias[t]);
  }
}

// ---------------- pooling + head fused ----------------
__global__ void k_poolhead(const unsigned short* __restrict__ h, const float* __restrict__ logit,
                           const int* __restrict__ gptr,
                           const float* __restrict__ w1, const float* __restrict__ b1,
                           const float* __restrict__ w2, const float* __restrict__ b2,
                           float* __restrict__ out){
  int g = blockIdx.x, t = threadIdx.x;   // 128
  int beg = gptr[g], end = gptr[g+1];
  __shared__ float red[128];
  __shared__ float prow[128];
  __shared__ float r1[128];
  __shared__ float m_sh, s_sh;
  float mx = -1e30f;
  for (int i = beg + t; i < end; i += 128) mx = fmaxf(mx, logit[i]);
  red[t] = mx; __syncthreads();
  for (int off = 64; off > 0; off >>= 1){ if (t < off) red[t] = fmaxf(red[t], red[t + off]); __syncthreads(); }
  if (t == 0) m_sh = red[0];
  __syncthreads();
  float sm = 0.f;
  for (int i = beg + t; i < end; i += 128) sm += __expf(logit[i] - m_sh);
  red[t] = sm; __syncthreads();
  for (int off = 64; off > 0; off >>= 1){ if (t < off) red[t] += red[t + off]; __syncthreads(); }
  if (t == 0) s_sh = red[0] + 1e-16f;
  __syncthreads();
  float acc = 0.f;
  for (int i = beg; i < end; i++){
    float w = __expf(logit[i] - m_sh) / s_sh;
    acc += w * b2f(h[(size_t)i*128 + t]);
  }
  prow[t] = acc;
  __syncthreads();
  float a = b1[t];
  for (int k = 0; k < 128; k++) a += prow[k]*w1[k*128 + t];
  a = fmaxf(a, 0.f);
  red[t] = a*w2[t*2 + 0]; r1[t] = a*w2[t*2 + 1];
  __syncthreads();
  for (int off = 64; off > 0; off >>= 1){
    if (t < off){ red[t] += red[t + off]; r1[t] += r1[t + off]; }
    __syncthreads();
  }
  if (t == 0){ out[g*2 + 0] = red[0] + b2[0]; out[g*2 + 1] = r1[0] + b2[1]; }
}

extern "C" void kernel_launch(void* const* d_in, const int* in_sizes, int n_in,
                              void* d_out, int out_size, void* d_ws, size_t ws_size,
                              hipStream_t stream) {
  const float* x        = (const float*)d_in[0];
  const int*   ei       = (const int*)  d_in[1];
  const int*   batch    = (const int*)  d_in[2];
  const float* gw1[4] = {(const float*)d_in[3],  (const float*)d_in[7],  (const float*)d_in[11], (const float*)d_in[15]};
  const float* gb1[4] = {(const float*)d_in[4],  (const float*)d_in[8],  (const float*)d_in[12], (const float*)d_in[16]};
  const float* gw2[4] = {(const float*)d_in[5],  (const float*)d_in[9],  (const float*)d_in[13], (const float*)d_in[17]};
  const float* gb2[4] = {(const float*)d_in[6],  (const float*)d_in[10], (const float*)d_in[14], (const float*)d_in[18]};
  const float* bng[5] = {(const float*)d_in[19], (const float*)d_in[21], (const float*)d_in[23], (const float*)d_in[25], (const float*)d_in[27]};
  const float* bnb[5] = {(const float*)d_in[20], (const float*)d_in[22], (const float*)d_in[24], (const float*)d_in[26], (const float*)d_in[28]};
  const float* gat_w    = (const float*)d_in[29];
  const float* gat_asrc = (const float*)d_in[30];
  const float* gat_adst = (const float*)d_in[31];
  const float* gat_bias = (const float*)d_in[32];
  const float* gate_w   = (const float*)d_in[33];
  const float* gate_b   = (const float*)d_in[34];
  const float* fc1_w    = (const float*)d_in[35];
  const float* fc1_b    = (const float*)d_in[36];
  const float* fc2_w    = (const float*)d_in[37];
  const float* fc2_b    = (const float*)d_in[38];
  const int* src = ei;
  const int* dst = ei + NE;

  char* wsb = (char*)d_ws;
  size_t off = 0;
  auto take = [&](size_t bytes) -> void* {
    void* p = wsb + off;
    off = (off + bytes + 255) & ~(size_t)255;
    return p;
  };
  unsigned short* hpre  = (unsigned short*)take((size_t)NN*512*2);
  unsigned short* hb    = (unsigned short*)take((size_t)NN*512*2);
  unsigned short* zh    = (unsigned short*)take((size_t)NN*1024*2);  // z16 | hid16; contiguous = xh16
  unsigned short* z16   = zh;
  unsigned short* hid16 = zh + (size_t)NN*512;
  unsigned short* xh16  = zh;
  unsigned short* xb    = (unsigned short*)take((size_t)NN*128*2);
  unsigned short* wt    = (unsigned short*)take((size_t)1000000*2);
  // zero-init region: deg, cnt, gdeg, statsA contiguous (ONE memset)
  int*    deg    = (int*)   take((size_t)NN*4);
  int*    cnt    = (int*)   take((size_t)NN*4);
  int*    gdeg   = (int*)   take((size_t)NG*4);
  double* statsA = (double*)take(2560*8);
  float*  a_s    = (float*) take((size_t)NN*8*4);
  float*  a_d    = (float*) take((size_t)NN*8*4);
  float*  logit  = (float*) take((size_t)NN*4);
  int*    rowptr = (int*)   take((size_t)(NN+1)*4);
  int*    gptr   = (int*)   take((size_t)(NG+1)*4);
  int*    csrc   = (int*)   take((size_t)NE*4);
  (void)ws_size; (void)n_in; (void)in_sizes; (void)out_size;

  unsigned short* wt_g1w1 = wt;
  unsigned short* wt_g1w2 = wt_g1w1 + 128*128;
  unsigned short* wt_g2w1 = wt_g1w2 + 128*128;
  unsigned short* wt_g2w2 = wt_g2w1 + 256*128;
  unsigned short* wt_g3w1 = wt_g2w2 + 256*256;
  unsigned short* wt_g3w2 = wt_g3w1 + 512*256;
  unsigned short* wt_g4w1 = wt_g3w2 + 512*512;
  unsigned short* wt_g4w2 = wt_g4w1 + 256*512;
  unsigned short* wt_gat  = wt_g4w2 + 256*256;

  double* st1 = statsA + 0;     // d=128
  double* st2 = statsA + 256;   // d=256
  double* st3 = statsA + 768;   // d=512
  double* st4 = statsA + 1792;  // d=256
  double* st5 = statsA + 2304;  // d=128

  hipMemsetAsync(deg, 0, (size_t)((char*)(statsA + 2560) - (char*)deg), stream);

  k_hist2<<<(NE + NN + 255)/256, 256, 0, stream>>>(dst, batch, deg, gdeg);
  k_scan2<<<2, 1024, 0, stream>>>(deg, rowptr, gdeg, gptr);
  k_fill<<<(NE + 255)/256, 256, 0, stream>>>(src, dst, rowptr, cnt, csrc);

  {
    WPrep P;
    const float* Ws[9] = {gw1[0], gw2[0], gw1[1], gw2[1], gw1[2], gw2[2], gw1[3], gw2[3], gat_w};
    unsigned short* Wts[9] = {wt_g1w1, wt_g1w2, wt_g2w1, wt_g2w2, wt_g3w1, wt_g3w2, wt_g4w1, wt_g4w2, wt_gat};
    int Ks[9]  = {128, 128, 128, 256, 256, 512, 512, 256, 256};
    int Nns[9] = {128, 128, 256, 256, 512, 512, 256, 256, 1024};
    int cum = 0;
    for (int i = 0; i < 9; i++){
      P.W[i] = Ws[i]; P.Wt[i] = Wts[i]; P.K[i] = Ks[i]; P.Nn[i] = Nns[i];
      P.tileStart[i] = cum;
      cum += (Ks[i] >> 6)*(Nns[i] >> 6);
    }
    P.tileStart[9] = cum;
    P.x = x; P.xb = (unsigned int*)xb;
    int xblocks = (NN*64 + 255)/256;
    k_prep2<<<cum + xblocks, 256, 0, stream>>>(P);
  }

  const int GM = (NN + 127) / 128;
  #define NP9 nullptr, nullptr, nullptr, nullptr
  #define NB3 nullptr, nullptr, nullptr

  // ---- GIN1: agg + fused MLP (stats st1) ----
  k_agg<0,64><<<NN/4, 256, 0, stream>>>((const unsigned int*)xb, rowptr, csrc, (unsigned int*)z16, nullptr, nullptr, nullptr, nullptr);
  k_gin1_mlp<<<GM, 256, 0, stream>>>(z16, wt_g1w1, gb1[0], wt_g1w2, gb2[0], hpre, st1, NN);

  // ---- GIN2: BN1 fused into gather ----
  k_agg<1,64><<<NN/4, 256, 0, stream>>>((const unsigned int*)hpre, rowptr, csrc, (unsigned int*)z16, st1, bng[0], bnb[0], nullptr);
  k_gemm_mfma<1,1,0,0,0><<<dim3(2, GM), 256, 0, stream>>>(z16, wt_g2w1, gb1[1], nullptr, hid16, nullptr, NP9, NB3, NN, 256, 128);
  k_gemm_mfma<0,1,1,0,0><<<dim3(2, GM), 256, 0, stream>>>(hid16, wt_g2w2, gb2[1], nullptr, hpre, st2, NP9, NB3, NN, 256, 256);

  // ---- GIN3: BN2 fused into gather ----
  k_agg<1,128><<<NN/2, 256, 0, stream>>>((const unsigned int*)hpre, rowptr, csrc, (unsigned int*)z16, st2, bng[1], bnb[1], nullptr);
  k_gemm_mfma<1,1,0,0,0><<<dim3(4, GM), 256, 0, stream>>>(z16, wt_g3w1, gb1[2], nullptr, hid16, nullptr, NP9, NB3, NN, 512, 256);
  k_gemm_mfma<0,1,1,0,0><<<dim3(4, GM), 256, 0, stream>>>(hid16, wt_g3w2, gb2[2], nullptr, hpre, st3, NP9, NB3, NN, 512, 512);

  // ---- GIN4: BN3 fused into w1 staging (BNA), agg post-w1, w2 (stats st4) ----
  k_gemm_mfma<0,1,0,0,1><<<dim3(2, GM), 256, 0, stream>>>(hpre, wt_g4w1, nullptr, nullptr, hid16, nullptr, NP9, st3, bng[2], bnb[2], NN, 256, 512);
  k_agg<2,128><<<NN/2, 256, 0, stream>>>((const unsigned int*)hid16, rowptr, csrc, (unsigned int*)z16, nullptr, nullptr, nullptr, gb1[3]);
  k_gemm_mfma<0,1,1,0,0><<<dim3(2, GM), 256, 0, stream>>>(z16, wt_g4w2, gb2[3], nullptr, hpre, st4, NP9, NB3, NN, 256, 256);

  // ---- GAT: BN4 fused into GEMM staging (BNA) + scores epilogue ----
  k_gemm_mfma<0,1,0,1,1><<<dim3(8, GM), 256, 0, stream>>>(hpre, wt_gat, nullptr, nullptr, xh16, nullptr, gat_asrc, gat_adst, a_s, a_d, st4, bng[3], bnb[3], NN, 1024, 256);
  k_gat_node256<<<NN, 256, 0, stream>>>(xh16, a_s, a_d, rowptr, csrc, gat_bias, hpre);
  k_bn_stats16<<<(NN + 63)/64, 128, 0, stream>>>(hpre, 128, st5);
  k_bn_relu_gate<<<(NN*128/8 + 255)/256, 256, 0, stream>>>(hpre, hb, NN*128/8, st5, bng[4], bnb[4], gate_w, gate_b, logit);

  // ---- pooling + head fused ----
  k_poolhead<<<NG, 128, 0, stream>>>(hb, logit, gptr, fc1_w, fc1_b, fc2_w, fc2_b, (float*)d_out);
}